// Round 12
// baseline (1654.257 us; speedup 1.0000x reference)
//
#include <hip/hip_runtime.h>
#include <hip/hip_bf16.h>
#include <cstdint>

typedef __bf16 bf16;
typedef bf16 bf16x4 __attribute__((ext_vector_type(4)));
typedef bf16 bf16x8 __attribute__((ext_vector_type(8)));
typedef float f32x4 __attribute__((ext_vector_type(4)));

#define B_  2048
#define E_  512
#define H_  512
#define V_  50257
#define K1_ 1024
#define VPAD_ 50432   // 197*256

__device__ __forceinline__ void gload_lds16(const void* g, void* l) {
  __builtin_amdgcn_global_load_lds(
      (const __attribute__((address_space(1))) void*)g,
      (__attribute__((address_space(3))) void*)l, 16, 0, 0);
}

__device__ __forceinline__ float wave_sum(float v) {
#pragma unroll
  for (int o = 32; o > 0; o >>= 1) v += __shfl_xor(v, o, 64);
  return v;
}

// ---------------------------------------------------------------------------
// prep_big: gru_in bf16 [2048][1024]; wzrh bf16 [1536][1024];
//           wob bf16 [VPAD][512] (zero-padded rows V_..VPAD_)
// ---------------------------------------------------------------------------
__global__ __launch_bounds__(256) void prep_big_kernel(
    const float* __restrict__ hprev, const float* __restrict__ x,
    const float* __restrict__ Wz, const float* __restrict__ Wr,
    const float* __restrict__ Wh, const float* __restrict__ Wo,
    bf16* __restrict__ gin, bf16* __restrict__ wzrh, bf16* __restrict__ wob)
{
  const int i = blockIdx.x * 256 + threadIdx.x;
  constexpr int N1 = B_ * K1_ / 4;        // 524288
  constexpr int N2 = 1536 * K1_ / 4;      // 393216
  constexpr int N3 = V_ * 512 / 4;        // 6432896
  if (i < N1) {
    int e = i * 4;
    int m = e >> 10, k = e & 1023;
    const float* src = (k < 512) ? (hprev + (size_t)m * 512 + k)
                                 : (x + (size_t)m * 512 + (k - 512));
    f32x4 v = *reinterpret_cast<const f32x4*>(src);
    bf16x4 t; t[0]=(bf16)v[0]; t[1]=(bf16)v[1]; t[2]=(bf16)v[2]; t[3]=(bf16)v[3];
    *reinterpret_cast<bf16x4*>(gin + e) = t;
  } else if (i < N1 + N2) {
    int e = (i - N1) * 4;
    int which = e >> 19;
    int off = e & ((1 << 19) - 1);
    const float* W = (which == 0) ? Wz : (which == 1) ? Wr : Wh;
    f32x4 v = *reinterpret_cast<const f32x4*>(W + off);
    bf16x4 t; t[0]=(bf16)v[0]; t[1]=(bf16)v[1]; t[2]=(bf16)v[2]; t[3]=(bf16)v[3];
    *reinterpret_cast<bf16x4*>(wzrh + e) = t;
  } else if (i < N1 + N2 + N3) {
    size_t e = (size_t)(i - N1 - N2) * 4;
    f32x4 v = *reinterpret_cast<const f32x4*>(Wo + e);
    bf16x4 t; t[0]=(bf16)v[0]; t[1]=(bf16)v[1]; t[2]=(bf16)v[2]; t[3]=(bf16)v[3];
    *reinterpret_cast<bf16x4*>(wob + e) = t;
  } else {
    size_t e = (size_t)V_ * 512 + (size_t)(i - N1 - N2 - N3) * 4;
    bf16x4 t = {};
    *reinterpret_cast<bf16x4*>(wob + e) = t;
  }
}

// ---------------------------------------------------------------------------
// gemm64: BM=64, BN=128, BK=64, 2-phase dbuf, 256 thr (4 waves, 2M x 2N).
// Same verified fragment/swizzle math as gemm_bf16_nt; grid fills the GPU
// for the small GEMMs (zr: 32x8=256 blocks, h: 32x4=128).
// ---------------------------------------------------------------------------
__global__ __launch_bounds__(256) void gemm64(
    const bf16* __restrict__ A, const bf16* __restrict__ Bm,
    float* __restrict__ C, int M, int N, int K)
{
  __shared__ bf16 As[2][64 * 64];    // 16 KB
  __shared__ bf16 Bs[2][128 * 64];   // 32 KB
  const int tid = threadIdx.x;
  const int wid = tid >> 6, lane = tid & 63;
  const int bm = blockIdx.x, bn = blockIdx.y;
  const int wm = (wid >> 1) * 32, wn = (wid & 1) * 64;
  f32x4 acc[2][4] = {};
  const size_t a_row0 = (size_t)bm * 64;
  const size_t b_row0 = (size_t)bn * 128;

  auto STAGE = [&](int buf, int k0) {
#pragma unroll
    for (int i = 0; i < 2; ++i) {          // A: 64 rows x 8 chunks = 512
      int base = i * 256 + wid * 64;
      int idx = base + lane;
      int row = idx >> 3;
      int col = ((idx & 7) ^ (row & 7)) << 3;
      gload_lds16(A + (a_row0 + row) * K + (k0 + col), &As[buf][base * 8]);
    }
#pragma unroll
    for (int i = 0; i < 4; ++i) {          // B: 128 rows x 8 chunks = 1024
      int base = i * 256 + wid * 64;
      int idx = base + lane;
      int row = idx >> 3;
      int col = ((idx & 7) ^ (row & 7)) << 3;
      gload_lds16(Bm + (b_row0 + row) * K + (k0 + col), &Bs[buf][base * 8]);
    }
  };

  auto COMPUTE = [&](int buf) {
#pragma unroll
    for (int kk = 0; kk < 2; ++kk) {
      bf16x8 af[2], bb[4];
#pragma unroll
      for (int i = 0; i < 2; ++i) {
        int ra = wm + i * 16 + (lane & 15);
        int ca = (kk * 32 + (lane >> 4) * 8) ^ ((ra & 7) << 3);
        af[i] = *reinterpret_cast<const bf16x8*>(&As[buf][ra * 64 + ca]);
      }
#pragma unroll
      for (int j = 0; j < 4; ++j) {
        int rb = wn + j * 16 + (lane & 15);
        int cb = (kk * 32 + (lane >> 4) * 8) ^ ((rb & 7) << 3);
        bb[j] = *reinterpret_cast<const bf16x8*>(&Bs[buf][rb * 64 + cb]);
      }
      __builtin_amdgcn_s_setprio(1);
#pragma unroll
      for (int i = 0; i < 2; ++i)
#pragma unroll
        for (int j = 0; j < 4; ++j)
          acc[i][j] = __builtin_amdgcn_mfma_f32_16x16x32_bf16(af[i], bb[j], acc[i][j], 0, 0, 0);
      __builtin_amdgcn_s_setprio(0);
    }
  };

  STAGE(0, 0);
  asm volatile("s_waitcnt vmcnt(0)" ::: "memory");
  __syncthreads();
  const int nt = K >> 6;
  int cur = 0;
  for (int t = 0; t < nt - 1; ++t) {
    STAGE(cur ^ 1, (t + 1) << 6);
    COMPUTE(cur);
    asm volatile("s_waitcnt vmcnt(0)" ::: "memory");
    __syncthreads();
    cur ^= 1;
  }
  COMPUTE(cur);

  const int r0 = (lane >> 4) * 4, cc = lane & 15;
#pragma unroll
  for (int i = 0; i < 2; ++i)
#pragma unroll
    for (int j = 0; j < 4; ++j) {
      int n = bn * 128 + wn + j * 16 + cc;
#pragma unroll
      for (int q = 0; q < 4; ++q) {
        int mm = bm * 64 + wm + i * 16 + r0 + q;
        C[(size_t)mm * N + n] = acc[i][j][q];
      }
    }
}

// ---------------------------------------------------------------------------
// LN(+bias) + sigmoid for z and r; emit z (fp32) and cand_in bf16 [h_prev*r|x]
// ---------------------------------------------------------------------------
__global__ __launch_bounds__(256) void ln_zr_kernel(
    const float* __restrict__ zrp,
    const float* __restrict__ bz, const float* __restrict__ br,
    const float* __restrict__ gz, const float* __restrict__ bez,
    const float* __restrict__ gr, const float* __restrict__ ber,
    const float* __restrict__ hprev, const float* __restrict__ x,
    float* __restrict__ zbuf, bf16* __restrict__ cand)
{
  const int m = blockIdx.x, tid = threadIdx.x;
  const int wid = tid >> 6, lane = tid & 63;
  float zv[2], rv[2];
  float s0 = 0, s1 = 0, s2 = 0, s3 = 0;
#pragma unroll
  for (int e = 0; e < 2; ++e) {
    int n = tid + e * 256;
    float a = zrp[(size_t)m * 1024 + n] + bz[n];
    float b = zrp[(size_t)m * 1024 + 512 + n] + br[n];
    zv[e] = a; rv[e] = b;
    s0 += a; s1 += a * a; s2 += b; s3 += b * b;
  }
  s0 = wave_sum(s0); s1 = wave_sum(s1); s2 = wave_sum(s2); s3 = wave_sum(s3);
  __shared__ float red[4][4];
  if (lane == 0) { red[wid][0] = s0; red[wid][1] = s1; red[wid][2] = s2; red[wid][3] = s3; }
  __syncthreads();
  float zs = red[0][0] + red[1][0] + red[2][0] + red[3][0];
  float zq = red[0][1] + red[1][1] + red[2][1] + red[3][1];
  float rs = red[0][2] + red[1][2] + red[2][2] + red[3][2];
  float rq = red[0][3] + red[1][3] + red[2][3] + red[3][3];
  float zm = zs * (1.f / 512.f), zvr = zq * (1.f / 512.f) - zm * zm;
  float rm = rs * (1.f / 512.f), rvr = rq * (1.f / 512.f) - rm * rm;
  float zrs_ = rsqrtf(zvr + 1e-5f), rrs = rsqrtf(rvr + 1e-5f);
#pragma unroll
  for (int e = 0; e < 2; ++e) {
    int n = tid + e * 256;
    float zval = 1.f / (1.f + expf(-((zv[e] - zm) * zrs_ * gz[n] + bez[n])));
    float rval = 1.f / (1.f + expf(-((rv[e] - rm) * rrs * gr[n] + ber[n])));
    zbuf[(size_t)m * 512 + n] = zval;
    cand[(size_t)m * 1024 + n] = (bf16)(hprev[(size_t)m * 512 + n] * rval);
    cand[(size_t)m * 1024 + 512 + n] = (bf16)(x[(size_t)m * 512 + n]);
  }
}

// ---------------------------------------------------------------------------
// LN(+bias) + tanh for h_new; h_t = (1-z)*h_prev + z*h_new
// ---------------------------------------------------------------------------
__global__ __launch_bounds__(256) void ln_h_kernel(
    const float* __restrict__ hpre, const float* __restrict__ bh,
    const float* __restrict__ gh, const float* __restrict__ beh,
    const float* __restrict__ zbuf, const float* __restrict__ hprev,
    float* __restrict__ outh, bf16* __restrict__ htb)
{
  const int m = blockIdx.x, tid = threadIdx.x;
  const int wid = tid >> 6, lane = tid & 63;
  float v[2];
  float s0 = 0, s1 = 0;
#pragma unroll
  for (int e = 0; e < 2; ++e) {
    int n = tid + e * 256;
    float a = hpre[(size_t)m * 512 + n] + bh[n];
    v[e] = a; s0 += a; s1 += a * a;
  }
  s0 = wave_sum(s0); s1 = wave_sum(s1);
  __shared__ float red[4][2];
  if (lane == 0) { red[wid][0] = s0; red[wid][1] = s1; }
  __syncthreads();
  float ss = red[0][0] + red[1][0] + red[2][0] + red[3][0];
  float sq = red[0][1] + red[1][1] + red[2][1] + red[3][1];
  float mean = ss * (1.f / 512.f), var = sq * (1.f / 512.f) - mean * mean;
  float rstd = rsqrtf(var + 1e-5f);
#pragma unroll
  for (int e = 0; e < 2; ++e) {
    int n = tid + e * 256;
    float hn = tanhf((v[e] - mean) * rstd * gh[n] + beh[n]);
    float z = zbuf[(size_t)m * 512 + n];
    float ht = (1.f - z) * hprev[(size_t)m * 512 + n] + z * hn;
    outh[(size_t)m * 512 + n] = ht;
    htb[(size_t)m * 512 + n] = (bf16)ht;
  }
}

// ---------------------------------------------------------------------------
// big GEMM v8: 256x256, BK=64, SINGLE 64 KB LDS buffer -> 2 blocks/CU
// (4 waves/SIMD: cross-block overlap of epilogue drain, prologue, barriers).
// Reg-staging: LOADR(t+1) issued before COMPUTE(t) (full-tile latency cover);
// ds_write after lgkm-only raw barrier — NO vmcnt drain anywhere (compiler
// emits a counted vmcnt before the ds_write register uses).
// Cached stores, row-contiguous (r7's nt-store 2x write bug fixed in r8).
// ---------------------------------------------------------------------------
__global__ __launch_bounds__(512, 4) void gemm_out256(
    const bf16* __restrict__ A, const bf16* __restrict__ Wb,
    const float* __restrict__ bo, float* __restrict__ Y)
{
  __shared__ bf16 smA[256 * 64];   // 32 KB
  __shared__ bf16 smB[256 * 64];   // 32 KB
  const int tid = threadIdx.x;
  const int lane = tid & 63;
  const int wid = tid >> 6;
  const int wr = wid >> 2, wc = wid & 3;            // 2M x 4N waves
  const int hw = blockIdx.x;
  const int logical = (hw & 7) * 197 + (hw >> 3);   // bijective XCD swizzle
  const int bm = logical & 7;                        // bm-inner: Wo-panel reuse
  const int bn = logical >> 3;
  const size_t a_row0 = (size_t)bm * 256;
  const size_t b_row0 = (size_t)bn * 256;
  f32x4 acc[8][4] = {};
  f32x4 stA[4], stB[4];

  int srow[4], scol[4];
#pragma unroll
  for (int s = 0; s < 4; ++s) {
    int idx = s * 512 + tid;
    srow[s] = idx >> 3;
    scol[s] = ((idx & 7) ^ (srow[s] & 7)) << 3;     // pre-swizzled source chunk
  }

  auto LOADR = [&](int kt) {                        // 8 global_load_dwordx4
    const int k0 = kt << 6;
#pragma unroll
    for (int s = 0; s < 4; ++s) {
      stA[s] = *reinterpret_cast<const f32x4*>(A  + (a_row0 + srow[s]) * 512 + k0 + scol[s]);
      stB[s] = *reinterpret_cast<const f32x4*>(Wb + (b_row0 + srow[s]) * 512 + k0 + scol[s]);
    }
  };
  auto WRITELDS = [&]() {                           // 8 ds_write_b128, linear
#pragma unroll
    for (int s = 0; s < 4; ++s) {
      int e = (s * 512 + tid) * 8;
      *reinterpret_cast<f32x4*>(&smA[e]) = stA[s];
      *reinterpret_cast<f32x4*>(&smB[e]) = stB[s];
    }
  };

  auto COMPUTE = [&]() {
#pragma unroll
    for (int kk = 0; kk < 2; ++kk) {
      bf16x8 a[8], b[4];
#pragma unroll
      for (int i = 0; i < 8; ++i) {
        int r = wr * 128 + i * 16 + (lane & 15);
        int ch = ((kk * 4 + (lane >> 4)) ^ (r & 7)) << 3;
        a[i] = *reinterpret_cast<const bf16x8*>(&smA[r * 64 + ch]);
      }
#pragma unroll
      for (int j = 0; j < 4; ++j) {
        int r = wc * 64 + j * 16 + (lane & 15);
        int ch = ((kk * 4 + (lane >> 4)) ^ (r & 7)) << 3;
        b[j] = *reinterpret_cast<const bf16x8*>(&smB[r * 64 + ch]);
      }
      __builtin_amdgcn_s_setprio(1);
#pragma unroll
      for (int i = 0; i < 8; ++i)
#pragma unroll
        for (int j = 0; j < 4; ++j)
          acc[i][j] = __builtin_amdgcn_mfma_f32_16x16x32_bf16(a[i], b[j], acc[i][j], 0, 0, 0);
      __builtin_amdgcn_s_setprio(0);
    }
  };

  // prologue: tile 0 into LDS (compiler inserts counted vmcnt before ds_write)
  LOADR(0);
  WRITELDS();
  asm volatile("s_waitcnt lgkmcnt(0)" ::: "memory");
  __builtin_amdgcn_s_barrier();

#pragma unroll 1
  for (int t = 0; t < 8; ++t) {
    if (t < 7) LOADR(t + 1);                 // in flight under entire compute
    COMPUTE();                               // ds_read + MFMA (compiler lgkm)
    asm volatile("s_waitcnt lgkmcnt(0)" ::: "memory");   // my reads retired
    __builtin_amdgcn_s_barrier();            // all waves done reading tile t
    if (t < 7) {
      WRITELDS();                            // counted vmcnt on stA/stB only
      asm volatile("s_waitcnt lgkmcnt(0)" ::: "memory"); // my writes visible
      __builtin_amdgcn_s_barrier();          // tile t+1 ready for all waves
    }
  }

  // epilogue: row-contiguous cached stores (j innermost)
  const int r0q = (lane >> 4) * 4, cc = lane & 15;
  const int rowbase = (int)a_row0 + wr * 128;
  const int colbase = (int)b_row0 + wc * 64;
  float bia[4]; bool val[4];
#pragma unroll
  for (int j = 0; j < 4; ++j) {
    int n = colbase + j * 16 + cc;
    val[j] = (n < V_);
    bia[j] = val[j] ? bo[n] : 0.f;
  }
#pragma unroll
  for (int i = 0; i < 8; ++i) {
#pragma unroll
    for (int q = 0; q < 4; ++q) {
      size_t rowoff = (size_t)(rowbase + i * 16 + r0q + q) * V_;
#pragma unroll
      for (int j = 0; j < 4; ++j) {
        if (val[j]) Y[rowoff + colbase + j * 16 + cc] = acc[i][j][q] + bia[j];
      }
    }
  }
}

// ---------------------------------------------------------------------------
// fallback path (ws too small): fp32 Wo reg-staged GEMM + simple prep
// ---------------------------------------------------------------------------
__global__ __launch_bounds__(256) void gemm_out_kernel(
    const bf16* __restrict__ A, const float* __restrict__ Wo,
    const float* __restrict__ bo, float* __restrict__ Y)
{
  __shared__ bf16 As[128 * 64];
  __shared__ bf16 Bs[128 * 64];
  constexpr int K = 512;
  const int tid = threadIdx.x;
  const int wid = tid >> 6, lane = tid & 63;
  const int bm = blockIdx.x, bn = blockIdx.y;
  const int wm = (wid >> 1) * 64, wn = (wid & 1) * 64;
  f32x4 acc[4][4] = {};

  for (int k0 = 0; k0 < K; k0 += 64) {
#pragma unroll
    for (int i = 0; i < 4; ++i) {
      int base = i * 256 + wid * 64;
      int idx = base + lane;
      int row = idx >> 3, col = (idx & 7) << 3;
      gload_lds16(A + ((size_t)bm * 128 + row) * K + (k0 + col), &As[base * 8]);
    }
#pragma unroll
    for (int i = 0; i < 8; ++i) {
      int idx = i * 256 + tid;
      int row = idx >> 4;
      int c4 = (idx & 15) * 4;
      int n = bn * 128 + row;
      int nc = (n < V_) ? n : (V_ - 1);
      f32x4 v = *reinterpret_cast<const f32x4*>(Wo + (size_t)nc * K + k0 + c4);
      bf16x4 t; t[0]=(bf16)v[0]; t[1]=(bf16)v[1]; t[2]=(bf16)v[2]; t[3]=(bf16)v[3];
      *reinterpret_cast<bf16x4*>(&Bs[row * 64 + c4]) = t;
    }
    asm volatile("s_waitcnt vmcnt(0)" ::: "memory");
    __syncthreads();
#pragma unroll
    for (int kk = 0; kk < 2; ++kk) {
      bf16x8 af[4], bb[4];
#pragma unroll
      for (int i = 0; i < 4; ++i)
        af[i] = *reinterpret_cast<const bf16x8*>(
            &As[(wm + i * 16 + (lane & 15)) * 64 + kk * 32 + (lane >> 4) * 8]);
#pragma unroll
      for (int j = 0; j < 4; ++j)
        bb[j] = *reinterpret_cast<const bf16x8*>(
            &Bs[(wn + j * 16 + (lane & 15)) * 64 + kk * 32 + (lane >> 4) * 8]);
#pragma unroll
      for (int i = 0; i < 4; ++i)
#pragma unroll
        for (int j = 0; j < 4; ++j)
          acc[i][j] = __builtin_amdgcn_mfma_f32_16x16x32_bf16(af[i], bb[j], acc[i][j], 0, 0, 0);
    }
    __syncthreads();
  }

  const int r0 = (lane >> 4) * 4, cc = lane & 15;
#pragma unroll
  for (int i = 0; i < 4; ++i)
#pragma unroll
    for (int j = 0; j < 4; ++j) {
      int n = bn * 128 + wn + j * 16 + cc;
      if (n < V_) {
        float bia = bo[n];
#pragma unroll
        for (int q = 0; q < 4; ++q) {
          int mm = bm * 128 + wm + i * 16 + r0 + q;
          Y[(size_t)mm * V_ + n] = acc[i][j][q] + bia;
        }
      }
    }
}

__global__ __launch_bounds__(256) void prep_kernel(
    const float* __restrict__ hprev, const float* __restrict__ x,
    const float* __restrict__ Wz, const float* __restrict__ Wr,
    const float* __restrict__ Wh,
    bf16* __restrict__ gin, bf16* __restrict__ wzrh)
{
  const int i = blockIdx.x * 256 + threadIdx.x;
  constexpr int N1 = B_ * K1_ / 4;
  constexpr int N2 = 1536 * K1_ / 4;
  if (i < N1) {
    int e = i * 4;
    int m = e >> 10, k = e & 1023;
    const float* src = (k < 512) ? (hprev + (size_t)m * 512 + k)
                                 : (x + (size_t)m * 512 + (k - 512));
    f32x4 v = *reinterpret_cast<const f32x4*>(src);
    bf16x4 t; t[0]=(bf16)v[0]; t[1]=(bf16)v[1]; t[2]=(bf16)v[2]; t[3]=(bf16)v[3];
    *reinterpret_cast<bf16x4*>(gin + e) = t;
  } else if (i < N1 + N2) {
    int e = (i - N1) * 4;
    int which = e >> 19;
    int off = e & ((1 << 19) - 1);
    const float* W = (which == 0) ? Wz : (which == 1) ? Wr : Wh;
    f32x4 v = *reinterpret_cast<const f32x4*>(W + off);
    bf16x4 t; t[0]=(bf16)v[0]; t[1]=(bf16)v[1]; t[2]=(bf16)v[2]; t[3]=(bf16)v[3];
    *reinterpret_cast<bf16x4*>(wzrh + e) = t;
  }
}

// ---------------------------------------------------------------------------
extern "C" void kernel_launch(void* const* d_in, const int* in_sizes, int n_in,
                              void* d_out, int out_size, void* d_ws, size_t ws_size,
                              hipStream_t stream) {
  const float* x     = (const float*)d_in[0];
  const float* hprev = (const float*)d_in[1];
  const float* Wz    = (const float*)d_in[2];
  const float* bz    = (const float*)d_in[3];
  const float* gz    = (const float*)d_in[4];
  const float* bez   = (const float*)d_in[5];
  const float* Wr    = (const float*)d_in[6];
  const float* br    = (const float*)d_in[7];
  const float* gr    = (const float*)d_in[8];
  const float* ber   = (const float*)d_in[9];
  const float* Wh    = (const float*)d_in[10];
  const float* bh    = (const float*)d_in[11];
  const float* gh    = (const float*)d_in[12];
  const float* beh   = (const float*)d_in[13];
  const float* Wo    = (const float*)d_in[14];
  const float* bo    = (const float*)d_in[15];

  float* out_h = (float*)d_out;
  float* out_y = out_h + (size_t)B_ * H_;

  char* ws = (char*)d_ws;
  bf16*  gin  = (bf16*)(ws);                      // 4 MB   [2048][1024]
  bf16*  wzrh = (bf16*)(ws + ((size_t)4 << 20));  // 3 MB   [1536][1024]
  float* zrp  = (float*)(ws + ((size_t)7 << 20)); // 8 MB   [2048][1024]
  float* zbuf = (float*)(ws + ((size_t)15 << 20));// 4 MB   [2048][512]
  bf16*  cand = (bf16*)(ws + ((size_t)19 << 20)); // 4 MB   [2048][1024]
  float* hpre = (float*)(ws + ((size_t)23 << 20));// 4 MB   [2048][512]
  bf16*  htb  = (bf16*)(ws + ((size_t)27 << 20)); // 2 MB   [2048][512]
  bf16*  wob  = (bf16*)(ws + ((size_t)29 << 20)); // 51.6 MB [VPAD_][512]

  constexpr size_t NEED = ((size_t)29 << 20) + (size_t)VPAD_ * 512 * 2;

  if (ws_size >= NEED) {
    prep_big_kernel<<<28800, 256, 0, stream>>>(hprev, x, Wz, Wr, Wh, Wo, gin, wzrh, wob);
  } else {
    prep_kernel<<<3584, 256, 0, stream>>>(hprev, x, Wz, Wr, Wh, gin, wzrh);
  }

  gemm64<<<dim3(32, 8), 256, 0, stream>>>(gin, wzrh, zrp, B_, 1024, K1_);
  ln_zr_kernel<<<B_, 256, 0, stream>>>(zrp, bz, br, gz, bez, gr, ber, hprev, x, zbuf, cand);
  gemm64<<<dim3(32, 4), 256, 0, stream>>>(cand, wzrh + (size_t)1024 * 1024, hpre, B_, 512, K1_);
  ln_h_kernel<<<B_, 256, 0, stream>>>(hpre, bh, gh, beh, zbuf, hprev, out_h, htb);

  if (ws_size >= NEED) {
    gemm_out256<<<1576, 512, 0, stream>>>(htb, wob, bo, out_y);
  } else {
    gemm_out_kernel<<<dim3(16, 393), 256, 0, stream>>>(htb, Wo, bo, out_y);
  }
}

// Round 13
// 317.820 us; speedup vs baseline: 5.2050x; 5.2050x over previous
//
#include <hip/hip_runtime.h>
#include <hip/hip_bf16.h>
#include <cstdint>

typedef __bf16 bf16;
typedef bf16 bf16x4 __attribute__((ext_vector_type(4)));
typedef bf16 bf16x8 __attribute__((ext_vector_type(8)));
typedef float f32x4 __attribute__((ext_vector_type(4)));

#define B_  2048
#define E_  512
#define H_  512
#define V_  50257
#define K1_ 1024
#define VPAD_ 50432   // 197*256

#define BAR() __builtin_amdgcn_s_barrier()
#define WAIT_LGKM0() do { asm volatile("s_waitcnt lgkmcnt(0)" ::: "memory"); \
                          __builtin_amdgcn_sched_barrier(0); } while (0)

__device__ __forceinline__ void gload_lds16(const void* g, void* l) {
  __builtin_amdgcn_global_load_lds(
      (const __attribute__((address_space(1))) void*)g,
      (__attribute__((address_space(3))) void*)l, 16, 0, 0);
}

__device__ __forceinline__ float wave_sum(float v) {
#pragma unroll
  for (int o = 32; o > 0; o >>= 1) v += __shfl_xor(v, o, 64);
  return v;
}

// ---------------------------------------------------------------------------
// prep_big: gru_in bf16 [2048][1024]; wzrh bf16 [1536][1024];
//           wob bf16 [VPAD][512] (zero-padded rows V_..VPAD_)
// ---------------------------------------------------------------------------
__global__ __launch_bounds__(256) void prep_big_kernel(
    const float* __restrict__ hprev, const float* __restrict__ x,
    const float* __restrict__ Wz, const float* __restrict__ Wr,
    const float* __restrict__ Wh, const float* __restrict__ Wo,
    bf16* __restrict__ gin, bf16* __restrict__ wzrh, bf16* __restrict__ wob)
{
  const int i = blockIdx.x * 256 + threadIdx.x;
  constexpr int N1 = B_ * K1_ / 4;        // 524288
  constexpr int N2 = 1536 * K1_ / 4;      // 393216
  constexpr int N3 = V_ * 512 / 4;        // 6432896
  if (i < N1) {
    int e = i * 4;
    int m = e >> 10, k = e & 1023;
    const float* src = (k < 512) ? (hprev + (size_t)m * 512 + k)
                                 : (x + (size_t)m * 512 + (k - 512));
    f32x4 v = *reinterpret_cast<const f32x4*>(src);
    bf16x4 t; t[0]=(bf16)v[0]; t[1]=(bf16)v[1]; t[2]=(bf16)v[2]; t[3]=(bf16)v[3];
    *reinterpret_cast<bf16x4*>(gin + e) = t;
  } else if (i < N1 + N2) {
    int e = (i - N1) * 4;
    int which = e >> 19;
    int off = e & ((1 << 19) - 1);
    const float* W = (which == 0) ? Wz : (which == 1) ? Wr : Wh;
    f32x4 v = *reinterpret_cast<const f32x4*>(W + off);
    bf16x4 t; t[0]=(bf16)v[0]; t[1]=(bf16)v[1]; t[2]=(bf16)v[2]; t[3]=(bf16)v[3];
    *reinterpret_cast<bf16x4*>(wzrh + e) = t;
  } else if (i < N1 + N2 + N3) {
    size_t e = (size_t)(i - N1 - N2) * 4;
    f32x4 v = *reinterpret_cast<const f32x4*>(Wo + e);
    bf16x4 t; t[0]=(bf16)v[0]; t[1]=(bf16)v[1]; t[2]=(bf16)v[2]; t[3]=(bf16)v[3];
    *reinterpret_cast<bf16x4*>(wob + e) = t;
  } else {
    size_t e = (size_t)V_ * 512 + (size_t)(i - N1 - N2 - N3) * 4;
    bf16x4 t = {};
    *reinterpret_cast<bf16x4*>(wob + e) = t;
  }
}

// ---------------------------------------------------------------------------
// gemm64: BM=64, BN=128, BK=64, 2-phase dbuf, 256 thr (4 waves, 2M x 2N).
// ---------------------------------------------------------------------------
__global__ __launch_bounds__(256) void gemm64(
    const bf16* __restrict__ A, const bf16* __restrict__ Bm,
    float* __restrict__ C, int M, int N, int K)
{
  __shared__ bf16 As[2][64 * 64];    // 16 KB
  __shared__ bf16 Bs[2][128 * 64];   // 32 KB
  const int tid = threadIdx.x;
  const int wid = tid >> 6, lane = tid & 63;
  const int bm = blockIdx.x, bn = blockIdx.y;
  const int wm = (wid >> 1) * 32, wn = (wid & 1) * 64;
  f32x4 acc[2][4] = {};
  const size_t a_row0 = (size_t)bm * 64;
  const size_t b_row0 = (size_t)bn * 128;

  auto STAGE = [&](int buf, int k0) {
#pragma unroll
    for (int i = 0; i < 2; ++i) {
      int base = i * 256 + wid * 64;
      int idx = base + lane;
      int row = idx >> 3;
      int col = ((idx & 7) ^ (row & 7)) << 3;
      gload_lds16(A + (a_row0 + row) * K + (k0 + col), &As[buf][base * 8]);
    }
#pragma unroll
    for (int i = 0; i < 4; ++i) {
      int base = i * 256 + wid * 64;
      int idx = base + lane;
      int row = idx >> 3;
      int col = ((idx & 7) ^ (row & 7)) << 3;
      gload_lds16(Bm + (b_row0 + row) * K + (k0 + col), &Bs[buf][base * 8]);
    }
  };

  auto COMPUTE = [&](int buf) {
#pragma unroll
    for (int kk = 0; kk < 2; ++kk) {
      bf16x8 af[2], bb[4];
#pragma unroll
      for (int i = 0; i < 2; ++i) {
        int ra = wm + i * 16 + (lane & 15);
        int ca = (kk * 32 + (lane >> 4) * 8) ^ ((ra & 7) << 3);
        af[i] = *reinterpret_cast<const bf16x8*>(&As[buf][ra * 64 + ca]);
      }
#pragma unroll
      for (int j = 0; j < 4; ++j) {
        int rb = wn + j * 16 + (lane & 15);
        int cb = (kk * 32 + (lane >> 4) * 8) ^ ((rb & 7) << 3);
        bb[j] = *reinterpret_cast<const bf16x8*>(&Bs[buf][rb * 64 + cb]);
      }
      __builtin_amdgcn_s_setprio(1);
#pragma unroll
      for (int i = 0; i < 2; ++i)
#pragma unroll
        for (int j = 0; j < 4; ++j)
          acc[i][j] = __builtin_amdgcn_mfma_f32_16x16x32_bf16(af[i], bb[j], acc[i][j], 0, 0, 0);
      __builtin_amdgcn_s_setprio(0);
    }
  };

  STAGE(0, 0);
  asm volatile("s_waitcnt vmcnt(0)" ::: "memory");
  __syncthreads();
  const int nt = K >> 6;
  int cur = 0;
  for (int t = 0; t < nt - 1; ++t) {
    STAGE(cur ^ 1, (t + 1) << 6);
    COMPUTE(cur);
    asm volatile("s_waitcnt vmcnt(0)" ::: "memory");
    __syncthreads();
    cur ^= 1;
  }
  COMPUTE(cur);

  const int r0 = (lane >> 4) * 4, cc = lane & 15;
#pragma unroll
  for (int i = 0; i < 2; ++i)
#pragma unroll
    for (int j = 0; j < 4; ++j) {
      int n = bn * 128 + wn + j * 16 + cc;
#pragma unroll
      for (int q = 0; q < 4; ++q) {
        int mm = bm * 64 + wm + i * 16 + r0 + q;
        C[(size_t)mm * N + n] = acc[i][j][q];
      }
    }
}

// ---------------------------------------------------------------------------
// LN(+bias) + sigmoid for z and r; emit z (fp32) and cand_in bf16 [h_prev*r|x]
// ---------------------------------------------------------------------------
__global__ __launch_bounds__(256) void ln_zr_kernel(
    const float* __restrict__ zrp,
    const float* __restrict__ bz, const float* __restrict__ br,
    const float* __restrict__ gz, const float* __restrict__ bez,
    const float* __restrict__ gr, const float* __restrict__ ber,
    const float* __restrict__ hprev, const float* __restrict__ x,
    float* __restrict__ zbuf, bf16* __restrict__ cand)
{
  const int m = blockIdx.x, tid = threadIdx.x;
  const int wid = tid >> 6, lane = tid & 63;
  float zv[2], rv[2];
  float s0 = 0, s1 = 0, s2 = 0, s3 = 0;
#pragma unroll
  for (int e = 0; e < 2; ++e) {
    int n = tid + e * 256;
    float a = zrp[(size_t)m * 1024 + n] + bz[n];
    float b = zrp[(size_t)m * 1024 + 512 + n] + br[n];
    zv[e] = a; rv[e] = b;
    s0 += a; s1 += a * a; s2 += b; s3 += b * b;
  }
  s0 = wave_sum(s0); s1 = wave_sum(s1); s2 = wave_sum(s2); s3 = wave_sum(s3);
  __shared__ float red[4][4];
  if (lane == 0) { red[wid][0] = s0; red[wid][1] = s1; red[wid][2] = s2; red[wid][3] = s3; }
  __syncthreads();
  float zs = red[0][0] + red[1][0] + red[2][0] + red[3][0];
  float zq = red[0][1] + red[1][1] + red[2][1] + red[3][1];
  float rs = red[0][2] + red[1][2] + red[2][2] + red[3][2];
  float rq = red[0][3] + red[1][3] + red[2][3] + red[3][3];
  float zm = zs * (1.f / 512.f), zvr = zq * (1.f / 512.f) - zm * zm;
  float rm = rs * (1.f / 512.f), rvr = rq * (1.f / 512.f) - rm * rm;
  float zrs_ = rsqrtf(zvr + 1e-5f), rrs = rsqrtf(rvr + 1e-5f);
#pragma unroll
  for (int e = 0; e < 2; ++e) {
    int n = tid + e * 256;
    float zval = 1.f / (1.f + expf(-((zv[e] - zm) * zrs_ * gz[n] + bez[n])));
    float rval = 1.f / (1.f + expf(-((rv[e] - rm) * rrs * gr[n] + ber[n])));
    zbuf[(size_t)m * 512 + n] = zval;
    cand[(size_t)m * 1024 + n] = (bf16)(hprev[(size_t)m * 512 + n] * rval);
    cand[(size_t)m * 1024 + 512 + n] = (bf16)(x[(size_t)m * 512 + n]);
  }
}

// ---------------------------------------------------------------------------
// LN(+bias) + tanh for h_new; h_t = (1-z)*h_prev + z*h_new
// ---------------------------------------------------------------------------
__global__ __launch_bounds__(256) void ln_h_kernel(
    const float* __restrict__ hpre, const float* __restrict__ bh,
    const float* __restrict__ gh, const float* __restrict__ beh,
    const float* __restrict__ zbuf, const float* __restrict__ hprev,
    float* __restrict__ outh, bf16* __restrict__ htb)
{
  const int m = blockIdx.x, tid = threadIdx.x;
  const int wid = tid >> 6, lane = tid & 63;
  float v[2];
  float s0 = 0, s1 = 0;
#pragma unroll
  for (int e = 0; e < 2; ++e) {
    int n = tid + e * 256;
    float a = hpre[(size_t)m * 512 + n] + bh[n];
    v[e] = a; s0 += a; s1 += a * a;
  }
  s0 = wave_sum(s0); s1 = wave_sum(s1);
  __shared__ float red[4][2];
  if (lane == 0) { red[wid][0] = s0; red[wid][1] = s1; }
  __syncthreads();
  float ss = red[0][0] + red[1][0] + red[2][0] + red[3][0];
  float sq = red[0][1] + red[1][1] + red[2][1] + red[3][1];
  float mean = ss * (1.f / 512.f), var = sq * (1.f / 512.f) - mean * mean;
  float rstd = rsqrtf(var + 1e-5f);
#pragma unroll
  for (int e = 0; e < 2; ++e) {
    int n = tid + e * 256;
    float hn = tanhf((v[e] - mean) * rstd * gh[n] + beh[n]);
    float z = zbuf[(size_t)m * 512 + n];
    float ht = (1.f - z) * hprev[(size_t)m * 512 + n] + z * hn;
    outh[(size_t)m * 512 + n] = ht;
    htb[(size_t)m * 512 + n] = (bf16)ht;
  }
}

// ---------------------------------------------------------------------------
// big GEMM v9: faithful 8-phase template (m201 port). 256x256, BK=64,
// 8 waves 2Mx4N (128x64/wave), LDS [2 parity][A,B][2 half][128x64] = 128 KB.
// buf0 = even K-steps, buf1 = odd. Per iteration (2 K-steps, 8 phases):
//   ph1: rd a[0..3],b[0..1](s)   | stage B0(s+1) | MFMA q(m0-3,n0-1) s
//   ph2: rd a[4..7](s)           | stage B1(s+1) | MFMA q(m4-7,n0-1) s
//   ph3: rd b[2..3](s)           | stage A0(s+2) | MFMA q(m0-3,n2-3) s
//   ph4:                         | stage B0(s+2) | vmcnt(4) | MFMA q(m4-7,n2-3) s
//   ph5: rd a[0..3],b[0..1](s+1) | stage A1(s+2) | MFMA ... s+1
//   ph6: rd a[4..7](s+1)         | stage B1(s+2) | MFMA
//   ph7: rd b[2..3](s+1)         | stage A0(s+3) | MFMA
//   ph8:                         | stage A1(s+3) | vmcnt(4) | MFMA
// Hazard ledger (verified): WAR — each half's last read is barrier-sealed
// >=1 phase before its overwrite-stage issue (A(s): done ph2, staged ph3/5;
// B(s): done ph3, staged ph4/6; buf1 A done ph6 staged ph7/8, B done ph7
// staged next-ph1/2). RAW — vmcnt(4)=2 stages outstanding at ph4/ph8
// guarantees: ph4 -> s+1 fully landed (staged >=4 stage-events earlier);
// ph8 -> s+2 fully landed. Tail iter: vmcnt(0) at ph4, no stages after ph2.
// ---------------------------------------------------------------------------
__global__ __launch_bounds__(512, 2) void gemm_out256(
    const bf16* __restrict__ A, const bf16* __restrict__ Wb,
    const float* __restrict__ bo, float* __restrict__ Y)
{
  __shared__ bf16 lds[2][2][2][128 * 64];   // [parity][op][half][row*64+col]
  const int tid = threadIdx.x;
  const int lane = tid & 63;
  const int wid = tid >> 6;
  const int wr = wid >> 2, wc = wid & 3;            // 2M x 4N waves
  const int hw = blockIdx.x;
  const int logical = (hw & 7) * 197 + (hw >> 3);   // bijective XCD swizzle
  const int bm = logical & 7;                        // bm-inner: Wo-panel reuse
  const int bn = logical >> 3;
  const size_t a_row0 = (size_t)bm * 256;
  const size_t b_row0 = (size_t)bn * 256;
  f32x4 acc[8][4] = {};

  // stage ONE half-tile (128 rows x 64 k) = 2 gload_lds16 per thread
  auto STAGE = [&](int p, int op, int h, int ks) {
    const bf16* src = op ? Wb : A;
    const size_t r0 = (op ? b_row0 : a_row0) + h * 128;
    const int k0 = ks << 6;
#pragma unroll
    for (int l = 0; l < 2; ++l) {
      int idx = l * 512 + tid;
      int row = idx >> 3;                     // 0..127
      int ch = ((idx & 7) ^ (row & 7)) << 3;  // pre-swizzled source chunk
      gload_lds16(src + (r0 + row) * 512 + k0 + ch,
                  &lds[p][op][h][(l * 512 + (tid & ~63)) * 8]);
    }
  };

  auto rdA = [&](int p, int i, int kk) -> bf16x8 {   // i in 0..7
    int lr = i * 16 + (lane & 15);                    // local row in half wr
    int ch = ((kk * 4 + (lane >> 4)) ^ (lr & 7)) << 3;
    return *reinterpret_cast<const bf16x8*>(&lds[p][0][wr][lr * 64 + ch]);
  };
  auto rdB = [&](int p, int j, int kk) -> bf16x8 {   // j in 0..3
    int gr = wc * 64 + j * 16 + (lane & 15);
    int lr = gr & 127;
    int ch = ((kk * 4 + (lane >> 4)) ^ (lr & 7)) << 3;
    return *reinterpret_cast<const bf16x8*>(&lds[p][1][wc >> 1][lr * 64 + ch]);
  };

  bf16x8 a0[4][2], a1[4][2], bb0[2][2], bb1[2][2];

  auto MM = [&](bf16x8 (&af)[4][2], bf16x8 (&bf)[2][2], int ib, int jb) {
    __builtin_amdgcn_s_setprio(1);
#pragma unroll
    for (int i = 0; i < 4; ++i)
#pragma unroll
      for (int j = 0; j < 2; ++j)
#pragma unroll
        for (int kk = 0; kk < 2; ++kk)
          acc[ib + i][jb + j] =
              __builtin_amdgcn_mfma_f32_16x16x32_bf16(af[i][kk], bf[j][kk],
                                                      acc[ib + i][jb + j], 0, 0, 0);
    __builtin_amdgcn_s_setprio(0);
  };

  // prologue: s0 full (A0,A1,B0,B1) + s1 A-halves; wait first 4 stages
  STAGE(0, 0, 0, 0); STAGE(0, 0, 1, 0); STAGE(0, 1, 0, 0); STAGE(0, 1, 1, 0);
  STAGE(1, 0, 0, 1); STAGE(1, 0, 1, 1);
  asm volatile("s_waitcnt vmcnt(4)" ::: "memory");
  BAR();

#pragma unroll 1
  for (int it = 0; it < 4; ++it) {
    const int s = 2 * it;
    const bool pre = (it < 3);
    // ---------------- step s (buf 0) ----------------
    // ph1
#pragma unroll
    for (int i = 0; i < 4; ++i) { a0[i][0] = rdA(0, i, 0); a0[i][1] = rdA(0, i, 1); }
#pragma unroll
    for (int j = 0; j < 2; ++j) { bb0[j][0] = rdB(0, j, 0); bb0[j][1] = rdB(0, j, 1); }
    STAGE(1, 1, 0, s + 1);
    BAR(); WAIT_LGKM0();
    MM(a0, bb0, 0, 0);
    BAR();
    // ph2
#pragma unroll
    for (int i = 0; i < 4; ++i) { a1[i][0] = rdA(0, 4 + i, 0); a1[i][1] = rdA(0, 4 + i, 1); }
    STAGE(1, 1, 1, s + 1);
    BAR(); WAIT_LGKM0();
    MM(a1, bb0, 4, 0);
    BAR();
    // ph3
#pragma unroll
    for (int j = 0; j < 2; ++j) { bb1[j][0] = rdB(0, 2 + j, 0); bb1[j][1] = rdB(0, 2 + j, 1); }
    if (pre) STAGE(0, 0, 0, s + 2);
    BAR(); WAIT_LGKM0();
    MM(a0, bb1, 0, 2);
    BAR();
    // ph4
    if (pre) { STAGE(0, 1, 0, s + 2);
               asm volatile("s_waitcnt vmcnt(4)" ::: "memory"); }
    else     { asm volatile("s_waitcnt vmcnt(0)" ::: "memory"); }
    BAR();
    MM(a1, bb1, 4, 2);
    BAR();
    // ---------------- step s+1 (buf 1) ----------------
    // ph5
#pragma unroll
    for (int i = 0; i < 4; ++i) { a0[i][0] = rdA(1, i, 0); a0[i][1] = rdA(1, i, 1); }
#pragma unroll
    for (int j = 0; j < 2; ++j) { bb0[j][0] = rdB(1, j, 0); bb0[j][1] = rdB(1, j, 1); }
    if (pre) STAGE(0, 0, 1, s + 2);
    BAR(); WAIT_LGKM0();
    MM(a0, bb0, 0, 0);
    BAR();
    // ph6
#pragma unroll
    for (int i = 0; i < 4; ++i) { a1[i][0] = rdA(1, 4 + i, 0); a1[i][1] = rdA(1, 4 + i, 1); }
    if (pre) STAGE(0, 1, 1, s + 2);
    BAR(); WAIT_LGKM0();
    MM(a1, bb0, 4, 0);
    BAR();
    // ph7
#pragma unroll
    for (int j = 0; j < 2; ++j) { bb1[j][0] = rdB(1, 2 + j, 0); bb1[j][1] = rdB(1, 2 + j, 1); }
    if (pre) STAGE(1, 0, 0, s + 3);
    BAR(); WAIT_LGKM0();
    MM(a0, bb1, 0, 2);
    BAR();
    // ph8
    if (pre) { STAGE(1, 0, 1, s + 3);
               asm volatile("s_waitcnt vmcnt(4)" ::: "memory"); }
    BAR();
    MM(a1, bb1, 4, 2);
    BAR();
  }

  // epilogue: row-contiguous cached stores (j innermost)
  const int r0q = (lane >> 4) * 4, cc = lane & 15;
  const int rowbase = (int)a_row0 + wr * 128;
  const int colbase = (int)b_row0 + wc * 64;
  float bia[4]; bool val[4];
#pragma unroll
  for (int j = 0; j < 4; ++j) {
    int n = colbase + j * 16 + cc;
    val[j] = (n < V_);
    bia[j] = val[j] ? bo[n] : 0.f;
  }
#pragma unroll
  for (int i = 0; i < 8; ++i) {
#pragma unroll
    for (int q = 0; q < 4; ++q) {
      size_t rowoff = (size_t)(rowbase + i * 16 + r0q + q) * V_;
#pragma unroll
      for (int j = 0; j < 4; ++j) {
        if (val[j]) Y[rowoff + colbase + j * 16 + cc] = acc[i][j][q] + bia[j];
      }
    }
  }
}

// ---------------------------------------------------------------------------
// fallback path (ws too small): fp32 Wo reg-staged GEMM + simple prep
// ---------------------------------------------------------------------------
__global__ __launch_bounds__(256) void gemm_out_kernel(
    const bf16* __restrict__ A, const float* __restrict__ Wo,
    const float* __restrict__ bo, float* __restrict__ Y)
{
  __shared__ bf16 As[128 * 64];
  __shared__ bf16 Bs[128 * 64];
  constexpr int K = 512;
  const int tid = threadIdx.x;
  const int wid = tid >> 6, lane = tid & 63;
  const int bm = blockIdx.x, bn = blockIdx.y;
  const int wm = (wid >> 1) * 64, wn = (wid & 1) * 64;
  f32x4 acc[4][4] = {};

  for (int k0 = 0; k0 < K; k0 += 64) {
#pragma unroll
    for (int i = 0; i < 4; ++i) {
      int base = i * 256 + wid * 64;
      int idx = base + lane;
      int row = idx >> 3, col = (idx & 7) << 3;
      gload_lds16(A + ((size_t)bm * 128 + row) * K + (k0 + col), &As[base * 8]);
    }
#pragma unroll
    for (int i = 0; i < 8; ++i) {
      int idx = i * 256 + tid;
      int row = idx >> 4;
      int c4 = (idx & 15) * 4;
      int n = bn * 128 + row;
      int nc = (n < V_) ? n : (V_ - 1);
      f32x4 v = *reinterpret_cast<const f32x4*>(Wo + (size_t)nc * K + k0 + c4);
      bf16x4 t; t[0]=(bf16)v[0]; t[1]=(bf16)v[1]; t[2]=(bf16)v[2]; t[3]=(bf16)v[3];
      *reinterpret_cast<bf16x4*>(&Bs[row * 64 + c4]) = t;
    }
    asm volatile("s_waitcnt vmcnt(0)" ::: "memory");
    __syncthreads();
#pragma unroll
    for (int kk = 0; kk < 2; ++kk) {
      bf16x8 af[4], bb[4];
#pragma unroll
      for (int i = 0; i < 4; ++i)
        af[i] = *reinterpret_cast<const bf16x8*>(
            &As[(wm + i * 16 + (lane & 15)) * 64 + kk * 32 + (lane >> 4) * 8]);
#pragma unroll
      for (int j = 0; j < 4; ++j)
        bb[j] = *reinterpret_cast<const bf16x8*>(
            &Bs[(wn + j * 16 + (lane & 15)) * 64 + kk * 32 + (lane >> 4) * 8]);
#pragma unroll
      for (int i = 0; i < 4; ++i)
#pragma unroll
        for (int j = 0; j < 4; ++j)
          acc[i][j] = __builtin_amdgcn_mfma_f32_16x16x32_bf16(af[i], bb[j], acc[i][j], 0, 0, 0);
    }
    __syncthreads();
  }

  const int r0 = (lane >> 4) * 4, cc = lane & 15;
#pragma unroll
  for (int i = 0; i < 4; ++i)
#pragma unroll
    for (int j = 0; j < 4; ++j) {
      int n = bn * 128 + wn + j * 16 + cc;
      if (n < V_) {
        float bia = bo[n];
#pragma unroll
        for (int q = 0; q < 4; ++q) {
          int mm = bm * 128 + wm + i * 16 + r0 + q;
          Y[(size_t)mm * V_ + n] = acc[i][j][q] + bia;
        }
      }
    }
}

__global__ __launch_bounds__(256) void prep_kernel(
    const float* __restrict__ hprev, const float* __restrict__ x,
    const float* __restrict__ Wz, const float* __restrict__ Wr,
    const float* __restrict__ Wh,
    bf16* __restrict__ gin, bf16* __restrict__ wzrh)
{
  const int i = blockIdx.x * 256 + threadIdx.x;
  constexpr int N1 = B_ * K1_ / 4;
  constexpr int N2 = 1536 * K1_ / 4;
  if (i < N1) {
    int e = i * 4;
    int m = e >> 10, k = e & 1023;
    const float* src = (k < 512) ? (hprev + (size_t)m * 512 + k)
                                 : (x + (size_t)m * 512 + (k - 512));
    f32x4 v = *reinterpret_cast<const f32x4*>(src);
    bf16x4 t; t[0]=(bf16)v[0]; t[1]=(bf16)v[1]; t[2]=(bf16)v[2]; t[3]=(bf16)v[3];
    *reinterpret_cast<bf16x4*>(gin + e) = t;
  } else if (i < N1 + N2) {
    int e = (i - N1) * 4;
    int which = e >> 19;
    int off = e & ((1 << 19) - 1);
    const float* W = (which == 0) ? Wz : (which == 1) ? Wr : Wh;
    f32x4 v = *reinterpret_cast<const f32x4*>(W + off);
    bf16x4 t; t[0]=(bf16)v[0]; t[1]=(bf16)v[1]; t[2]=(bf16)v[2]; t[3]=(bf16)v[3];
    *reinterpret_cast<bf16x4*>(wzrh + e) = t;
  }
}

// ---------------------------------------------------------------------------
extern "C" void kernel_launch(void* const* d_in, const int* in_sizes, int n_in,
                              void* d_out, int out_size, void* d_ws, size_t ws_size,
                              hipStream_t stream) {
  const float* x     = (const float*)d_in[0];
  const float* hprev = (const float*)d_in[1];
  const float* Wz    = (const float*)d_in[2];
  const float* bz    = (const float*)d_in[3];
  const float* gz    = (const float*)d_in[4];
  const float* bez   = (const float*)d_in[5];
  const float* Wr    = (const float*)d_in[6];
  const float* br    = (const float*)d_in[7];
  const float* gr    = (const float*)d_in[8];
  const float* ber   = (const float*)d_in[9];
  const float* Wh    = (const float*)d_in[10];
  const float* bh    = (const float*)d_in[11];
  const float* gh    = (const float*)d_in[12];
  const float* beh   = (const float*)d_in[13];
  const float* Wo    = (const float*)d_in[14];
  const float* bo    = (const float*)d_in[15];

  float* out_h = (float*)d_out;
  float* out_y = out_h + (size_t)B_ * H_;

  char* ws = (char*)d_ws;
  bf16*  gin  = (bf16*)(ws);                      // 4 MB   [2048][1024]
  bf16*  wzrh = (bf16*)(ws + ((size_t)4 << 20));  // 3 MB   [1536][1024]
  float* zrp  = (float*)(ws + ((size_t)7 << 20)); // 8 MB   [2048][1024]
  float* zbuf = (float*)(ws + ((size_t)15 << 20));// 4 MB   [2048][512]
  bf16*  cand = (bf16*)(ws + ((size_t)19 << 20)); // 4 MB   [2048][1024]
  float* hpre = (float*)(ws + ((size_t)23 << 20));// 4 MB   [2048][512]
  bf16*  htb  = (bf16*)(ws + ((size_t)27 << 20)); // 2 MB   [2048][512]
  bf16*  wob  = (bf16*)(ws + ((size_t)29 << 20)); // 51.6 MB [VPAD_][512]

  constexpr size_t NEED = ((size_t)29 << 20) + (size_t)VPAD_ * 512 * 2;

  if (ws_size >= NEED) {
    prep_big_kernel<<<28800, 256, 0, stream>>>(hprev, x, Wz, Wr, Wh, Wo, gin, wzrh, wob);
  } else {
    prep_kernel<<<3584, 256, 0, stream>>>(hprev, x, Wz, Wr, Wh, gin, wzrh);
  }

  gemm64<<<dim3(32, 8), 256, 0, stream>>>(gin, wzrh, zrp, B_, 1024, K1_);
  ln_zr_kernel<<<B_, 256, 0, stream>>>(zrp, bz, br, gz, bez, gr, ber, hprev, x, zbuf, cand);
  gemm64<<<dim3(32, 4), 256, 0, stream>>>(cand, wzrh + (size_t)1024 * 1024, hpre, B_, 512, K1_);
  ln_h_kernel<<<B_, 256, 0, stream>>>(hpre, bh, gh, beh, zbuf, hprev, out_h, htb);

  if (ws_size >= NEED) {
    gemm_out256<<<1576, 512, 0, stream>>>(htb, wob, bo, out_y);
  } else {
    gemm_out_kernel<<<dim3(16, 393), 256, 0, stream>>>(htb, Wo, bo, out_y);
  }
}

// Round 14
// 309.475 us; speedup vs baseline: 5.3454x; 1.0270x over previous
//
#include <hip/hip_runtime.h>
#include <hip/hip_bf16.h>
#include <cstdint>

typedef __bf16 bf16;
typedef bf16 bf16x4 __attribute__((ext_vector_type(4)));
typedef bf16 bf16x8 __attribute__((ext_vector_type(8)));
typedef float f32x4 __attribute__((ext_vector_type(4)));

#define B_  2048
#define E_  512
#define H_  512
#define V_  50257
#define K1_ 1024
#define VPAD_ 50432   // 197*256

// Wo conversion split (float4 units)
#define CONV_TOT  6432896   // V_*512/4
#define CONV_PAD  6455296   // VPAD_*512/4
#define CONV_HALF 3216448

#define BAR() __builtin_amdgcn_s_barrier()
#define WAIT_LGKM0() do { asm volatile("s_waitcnt lgkmcnt(0)" ::: "memory"); \
                          __builtin_amdgcn_sched_barrier(0); } while (0)

__device__ __forceinline__ void gload_lds16(const void* g, void* l) {
  __builtin_amdgcn_global_load_lds(
      (const __attribute__((address_space(1))) void*)g,
      (__attribute__((address_space(3))) void*)l, 16, 0, 0);
}

__device__ __forceinline__ float wave_sum(float v) {
#pragma unroll
  for (int o = 32; o > 0; o >>= 1) v += __shfl_xor(v, o, 64);
  return v;
}

__device__ __forceinline__ void cvt_store4(const float* __restrict__ src,
                                           bf16* __restrict__ dst, size_t e) {
  f32x4 v = *reinterpret_cast<const f32x4*>(src + e);
  bf16x4 t; t[0]=(bf16)v[0]; t[1]=(bf16)v[1]; t[2]=(bf16)v[2]; t[3]=(bf16)v[3];
  *reinterpret_cast<bf16x4*>(dst + e) = t;
}

// ---------------------------------------------------------------------------
// prep_small: gru_in bf16 [2048][1024]; wzrh bf16 [1536][1024]  (~7.5 MB)
// ---------------------------------------------------------------------------
__global__ __launch_bounds__(256) void prep_kernel(
    const float* __restrict__ hprev, const float* __restrict__ x,
    const float* __restrict__ Wz, const float* __restrict__ Wr,
    const float* __restrict__ Wh,
    bf16* __restrict__ gin, bf16* __restrict__ wzrh)
{
  const int i = blockIdx.x * 256 + threadIdx.x;
  constexpr int N1 = B_ * K1_ / 4;
  constexpr int N2 = 1536 * K1_ / 4;
  if (i < N1) {
    int e = i * 4;
    int m = e >> 10, k = e & 1023;
    const float* src = (k < 512) ? (hprev + (size_t)m * 512 + k)
                                 : (x + (size_t)m * 512 + (k - 512));
    f32x4 v = *reinterpret_cast<const f32x4*>(src);
    bf16x4 t; t[0]=(bf16)v[0]; t[1]=(bf16)v[1]; t[2]=(bf16)v[2]; t[3]=(bf16)v[3];
    *reinterpret_cast<bf16x4*>(gin + e) = t;
  } else if (i < N1 + N2) {
    int e = (i - N1) * 4;
    int which = e >> 19;
    int off = e & ((1 << 19) - 1);
    const float* W = (which == 0) ? Wz : (which == 1) ? Wr : Wh;
    f32x4 v = *reinterpret_cast<const f32x4*>(W + off);
    bf16x4 t; t[0]=(bf16)v[0]; t[1]=(bf16)v[1]; t[2]=(bf16)v[2]; t[3]=(bf16)v[3];
    *reinterpret_cast<bf16x4*>(wzrh + e) = t;
  }
}

// ---------------------------------------------------------------------------
// gemm64_zr: BM=64, BN=128, BK=64 GEMM for z/r pre-acts (M=2048,N=1024,K=1024)
// 1-D grid: blocks [0,256) do the GEMM; blocks [256, 256+2048) convert the
// FIRST half of Wo fp32 -> wob bf16 (hidden under the GEMM).
// ---------------------------------------------------------------------------
__global__ __launch_bounds__(256) void gemm64_zr(
    const bf16* __restrict__ A, const bf16* __restrict__ Bm,
    float* __restrict__ C,
    const float* __restrict__ Wo, bf16* __restrict__ wob)
{
  const int bx = blockIdx.x;
  const int tid = threadIdx.x;
  if (bx >= 256) {               // Wo conversion, first half
    const size_t cb = bx - 256;
    for (size_t idx = cb * 256 + tid; idx < CONV_HALF; idx += (size_t)2048 * 256)
      cvt_store4(Wo, wob, idx * 4);
    return;
  }
  constexpr int N = 1024, K = K1_;
  __shared__ bf16 As[2][64 * 64];
  __shared__ bf16 Bs[2][128 * 64];
  const int wid = tid >> 6, lane = tid & 63;
  const int bm = bx & 31, bn = bx >> 5;
  const int wm = (wid >> 1) * 32, wn = (wid & 1) * 64;
  f32x4 acc[2][4] = {};
  const size_t a_row0 = (size_t)bm * 64;
  const size_t b_row0 = (size_t)bn * 128;

  auto STAGE = [&](int buf, int k0) {
#pragma unroll
    for (int i = 0; i < 2; ++i) {
      int base = i * 256 + wid * 64;
      int idx = base + lane;
      int row = idx >> 3;
      int col = ((idx & 7) ^ (row & 7)) << 3;
      gload_lds16(A + (a_row0 + row) * K + (k0 + col), &As[buf][base * 8]);
    }
#pragma unroll
    for (int i = 0; i < 4; ++i) {
      int base = i * 256 + wid * 64;
      int idx = base + lane;
      int row = idx >> 3;
      int col = ((idx & 7) ^ (row & 7)) << 3;
      gload_lds16(Bm + (b_row0 + row) * K + (k0 + col), &Bs[buf][base * 8]);
    }
  };

  auto COMPUTE = [&](int buf) {
#pragma unroll
    for (int kk = 0; kk < 2; ++kk) {
      bf16x8 af[2], bb[4];
#pragma unroll
      for (int i = 0; i < 2; ++i) {
        int ra = wm + i * 16 + (lane & 15);
        int ca = (kk * 32 + (lane >> 4) * 8) ^ ((ra & 7) << 3);
        af[i] = *reinterpret_cast<const bf16x8*>(&As[buf][ra * 64 + ca]);
      }
#pragma unroll
      for (int j = 0; j < 4; ++j) {
        int rb = wn + j * 16 + (lane & 15);
        int cb2 = (kk * 32 + (lane >> 4) * 8) ^ ((rb & 7) << 3);
        bb[j] = *reinterpret_cast<const bf16x8*>(&Bs[buf][rb * 64 + cb2]);
      }
      __builtin_amdgcn_s_setprio(1);
#pragma unroll
      for (int i = 0; i < 2; ++i)
#pragma unroll
        for (int j = 0; j < 4; ++j)
          acc[i][j] = __builtin_amdgcn_mfma_f32_16x16x32_bf16(af[i], bb[j], acc[i][j], 0, 0, 0);
      __builtin_amdgcn_s_setprio(0);
    }
  };

  STAGE(0, 0);
  asm volatile("s_waitcnt vmcnt(0)" ::: "memory");
  __syncthreads();
  const int nt = K >> 6;
  int cur = 0;
  for (int t = 0; t < nt - 1; ++t) {
    STAGE(cur ^ 1, (t + 1) << 6);
    COMPUTE(cur);
    asm volatile("s_waitcnt vmcnt(0)" ::: "memory");
    __syncthreads();
    cur ^= 1;
  }
  COMPUTE(cur);

  const int r0 = (lane >> 4) * 4, cc = lane & 15;
#pragma unroll
  for (int i = 0; i < 2; ++i)
#pragma unroll
    for (int j = 0; j < 4; ++j) {
      int n = bn * 128 + wn + j * 16 + cc;
#pragma unroll
      for (int q = 0; q < 4; ++q) {
        int mm = bm * 64 + wm + i * 16 + r0 + q;
        C[(size_t)mm * N + n] = acc[i][j][q];
      }
    }
}

// ---------------------------------------------------------------------------
// gemm64 (generic, for h pre-act): BM=64, BN=128, BK=64
// ---------------------------------------------------------------------------
__global__ __launch_bounds__(256) void gemm64(
    const bf16* __restrict__ A, const bf16* __restrict__ Bm,
    float* __restrict__ C, int M, int N, int K)
{
  __shared__ bf16 As[2][64 * 64];
  __shared__ bf16 Bs[2][128 * 64];
  const int tid = threadIdx.x;
  const int wid = tid >> 6, lane = tid & 63;
  const int bm = blockIdx.x, bn = blockIdx.y;
  const int wm = (wid >> 1) * 32, wn = (wid & 1) * 64;
  f32x4 acc[2][4] = {};
  const size_t a_row0 = (size_t)bm * 64;
  const size_t b_row0 = (size_t)bn * 128;

  auto STAGE = [&](int buf, int k0) {
#pragma unroll
    for (int i = 0; i < 2; ++i) {
      int base = i * 256 + wid * 64;
      int idx = base + lane;
      int row = idx >> 3;
      int col = ((idx & 7) ^ (row & 7)) << 3;
      gload_lds16(A + (a_row0 + row) * K + (k0 + col), &As[buf][base * 8]);
    }
#pragma unroll
    for (int i = 0; i < 4; ++i) {
      int base = i * 256 + wid * 64;
      int idx = base + lane;
      int row = idx >> 3;
      int col = ((idx & 7) ^ (row & 7)) << 3;
      gload_lds16(Bm + (b_row0 + row) * K + (k0 + col), &Bs[buf][base * 8]);
    }
  };

  auto COMPUTE = [&](int buf) {
#pragma unroll
    for (int kk = 0; kk < 2; ++kk) {
      bf16x8 af[2], bb[4];
#pragma unroll
      for (int i = 0; i < 2; ++i) {
        int ra = wm + i * 16 + (lane & 15);
        int ca = (kk * 32 + (lane >> 4) * 8) ^ ((ra & 7) << 3);
        af[i] = *reinterpret_cast<const bf16x8*>(&As[buf][ra * 64 + ca]);
      }
#pragma unroll
      for (int j = 0; j < 4; ++j) {
        int rb = wn + j * 16 + (lane & 15);
        int cb = (kk * 32 + (lane >> 4) * 8) ^ ((rb & 7) << 3);
        bb[j] = *reinterpret_cast<const bf16x8*>(&Bs[buf][rb * 64 + cb]);
      }
      __builtin_amdgcn_s_setprio(1);
#pragma unroll
      for (int i = 0; i < 2; ++i)
#pragma unroll
        for (int j = 0; j < 4; ++j)
          acc[i][j] = __builtin_amdgcn_mfma_f32_16x16x32_bf16(af[i], bb[j], acc[i][j], 0, 0, 0);
      __builtin_amdgcn_s_setprio(0);
    }
  };

  STAGE(0, 0);
  asm volatile("s_waitcnt vmcnt(0)" ::: "memory");
  __syncthreads();
  const int nt = K >> 6;
  int cur = 0;
  for (int t = 0; t < nt - 1; ++t) {
    STAGE(cur ^ 1, (t + 1) << 6);
    COMPUTE(cur);
    asm volatile("s_waitcnt vmcnt(0)" ::: "memory");
    __syncthreads();
    cur ^= 1;
  }
  COMPUTE(cur);

  const int r0 = (lane >> 4) * 4, cc = lane & 15;
#pragma unroll
  for (int i = 0; i < 2; ++i)
#pragma unroll
    for (int j = 0; j < 4; ++j) {
      int n = bn * 128 + wn + j * 16 + cc;
#pragma unroll
      for (int q = 0; q < 4; ++q) {
        int mm = bm * 64 + wm + i * 16 + r0 + q;
        C[(size_t)mm * N + n] = acc[i][j][q];
      }
    }
}

// ---------------------------------------------------------------------------
// LN(+bias) + sigmoid for z and r; emit z (fp32) and cand_in bf16 [h_prev*r|x]
// blocks [2048, 4096) convert the SECOND half of Wo + zero-pad.
// ---------------------------------------------------------------------------
__global__ __launch_bounds__(256) void ln_zr_kernel(
    const float* __restrict__ zrp,
    const float* __restrict__ bz, const float* __restrict__ br,
    const float* __restrict__ gz, const float* __restrict__ bez,
    const float* __restrict__ gr, const float* __restrict__ ber,
    const float* __restrict__ hprev, const float* __restrict__ x,
    float* __restrict__ zbuf, bf16* __restrict__ cand,
    const float* __restrict__ Wo, bf16* __restrict__ wob)
{
  const int bx = blockIdx.x, tid = threadIdx.x;
  if (bx >= 2048) {              // Wo conversion, second half + pad
    const size_t cb = bx - 2048;
    for (size_t idx = CONV_HALF + cb * 256 + tid; idx < CONV_PAD;
         idx += (size_t)2048 * 256) {
      if (idx < CONV_TOT) {
        cvt_store4(Wo, wob, idx * 4);
      } else {
        bf16x4 t = {};
        *reinterpret_cast<bf16x4*>(wob + idx * 4) = t;
      }
    }
    return;
  }
  const int m = bx;
  const int wid = tid >> 6, lane = tid & 63;
  float zv[2], rv[2];
  float s0 = 0, s1 = 0, s2 = 0, s3 = 0;
#pragma unroll
  for (int e = 0; e < 2; ++e) {
    int n = tid + e * 256;
    float a = zrp[(size_t)m * 1024 + n] + bz[n];
    float b = zrp[(size_t)m * 1024 + 512 + n] + br[n];
    zv[e] = a; rv[e] = b;
    s0 += a; s1 += a * a; s2 += b; s3 += b * b;
  }
  s0 = wave_sum(s0); s1 = wave_sum(s1); s2 = wave_sum(s2); s3 = wave_sum(s3);
  __shared__ float red[4][4];
  if (lane == 0) { red[wid][0] = s0; red[wid][1] = s1; red[wid][2] = s2; red[wid][3] = s3; }
  __syncthreads();
  float zs = red[0][0] + red[1][0] + red[2][0] + red[3][0];
  float zq = red[0][1] + red[1][1] + red[2][1] + red[3][1];
  float rs = red[0][2] + red[1][2] + red[2][2] + red[3][2];
  float rq = red[0][3] + red[1][3] + red[2][3] + red[3][3];
  float zm = zs * (1.f / 512.f), zvr = zq * (1.f / 512.f) - zm * zm;
  float rm = rs * (1.f / 512.f), rvr = rq * (1.f / 512.f) - rm * rm;
  float zrs_ = rsqrtf(zvr + 1e-5f), rrs = rsqrtf(rvr + 1e-5f);
#pragma unroll
  for (int e = 0; e < 2; ++e) {
    int n = tid + e * 256;
    float zval = 1.f / (1.f + expf(-((zv[e] - zm) * zrs_ * gz[n] + bez[n])));
    float rval = 1.f / (1.f + expf(-((rv[e] - rm) * rrs * gr[n] + ber[n])));
    zbuf[(size_t)m * 512 + n] = zval;
    cand[(size_t)m * 1024 + n] = (bf16)(hprev[(size_t)m * 512 + n] * rval);
    cand[(size_t)m * 1024 + 512 + n] = (bf16)(x[(size_t)m * 512 + n]);
  }
}

// ---------------------------------------------------------------------------
// LN(+bias) + tanh for h_new; h_t = (1-z)*h_prev + z*h_new
// ---------------------------------------------------------------------------
__global__ __launch_bounds__(256) void ln_h_kernel(
    const float* __restrict__ hpre, const float* __restrict__ bh,
    const float* __restrict__ gh, const float* __restrict__ beh,
    const float* __restrict__ zbuf, const float* __restrict__ hprev,
    float* __restrict__ outh, bf16* __restrict__ htb)
{
  const int m = blockIdx.x, tid = threadIdx.x;
  const int wid = tid >> 6, lane = tid & 63;
  float v[2];
  float s0 = 0, s1 = 0;
#pragma unroll
  for (int e = 0; e < 2; ++e) {
    int n = tid + e * 256;
    float a = hpre[(size_t)m * 512 + n] + bh[n];
    v[e] = a; s0 += a; s1 += a * a;
  }
  s0 = wave_sum(s0); s1 = wave_sum(s1);
  __shared__ float red[4][2];
  if (lane == 0) { red[wid][0] = s0; red[wid][1] = s1; }
  __syncthreads();
  float ss = red[0][0] + red[1][0] + red[2][0] + red[3][0];
  float sq = red[0][1] + red[1][1] + red[2][1] + red[3][1];
  float mean = ss * (1.f / 512.f), var = sq * (1.f / 512.f) - mean * mean;
  float rstd = rsqrtf(var + 1e-5f);
#pragma unroll
  for (int e = 0; e < 2; ++e) {
    int n = tid + e * 256;
    float hn = tanhf((v[e] - mean) * rstd * gh[n] + beh[n]);
    float z = zbuf[(size_t)m * 512 + n];
    float ht = (1.f - z) * hprev[(size_t)m * 512 + n] + z * hn;
    outh[(size_t)m * 512 + n] = ht;
    htb[(size_t)m * 512 + n] = (bf16)ht;
  }
}

// ---------------------------------------------------------------------------
// big GEMM v9b: 8-phase template (r13, passing) with fully-unrolled K loop.
// 256x256, BK=64, 8 waves 2Mx4N, LDS [parity][op][half][128x64] = 128 KB.
// Hazard ledger unchanged from r13 (verified there).
// ---------------------------------------------------------------------------
__global__ __launch_bounds__(512, 2) void gemm_out256(
    const bf16* __restrict__ A, const bf16* __restrict__ Wb,
    const float* __restrict__ bo, float* __restrict__ Y)
{
  __shared__ bf16 lds[2][2][2][128 * 64];
  const int tid = threadIdx.x;
  const int lane = tid & 63;
  const int wid = tid >> 6;
  const int wr = wid >> 2, wc = wid & 3;
  const int hw = blockIdx.x;
  const int logical = (hw & 7) * 197 + (hw >> 3);
  const int bm = logical & 7;
  const int bn = logical >> 3;
  const size_t a_row0 = (size_t)bm * 256;
  const size_t b_row0 = (size_t)bn * 256;
  f32x4 acc[8][4] = {};

  auto STAGE = [&](int p, int op, int h, int ks) {
    const bf16* src = op ? Wb : A;
    const size_t r0 = (op ? b_row0 : a_row0) + h * 128;
    const int k0 = ks << 6;
#pragma unroll
    for (int l = 0; l < 2; ++l) {
      int idx = l * 512 + tid;
      int row = idx >> 3;
      int ch = ((idx & 7) ^ (row & 7)) << 3;
      gload_lds16(src + (r0 + row) * 512 + k0 + ch,
                  &lds[p][op][h][(l * 512 + (tid & ~63)) * 8]);
    }
  };

  auto rdA = [&](int p, int i, int kk) -> bf16x8 {
    int lr = i * 16 + (lane & 15);
    int ch = ((kk * 4 + (lane >> 4)) ^ (lr & 7)) << 3;
    return *reinterpret_cast<const bf16x8*>(&lds[p][0][wr][lr * 64 + ch]);
  };
  auto rdB = [&](int p, int j, int kk) -> bf16x8 {
    int gr = wc * 64 + j * 16 + (lane & 15);
    int lr = gr & 127;
    int ch = ((kk * 4 + (lane >> 4)) ^ (lr & 7)) << 3;
    return *reinterpret_cast<const bf16x8*>(&lds[p][1][wc >> 1][lr * 64 + ch]);
  };

  bf16x8 a0[4][2], a1[4][2], bb0[2][2], bb1[2][2];

  auto MM = [&](bf16x8 (&af)[4][2], bf16x8 (&bf)[2][2], int ib, int jb) {
    __builtin_amdgcn_s_setprio(1);
#pragma unroll
    for (int i = 0; i < 4; ++i)
#pragma unroll
      for (int j = 0; j < 2; ++j)
#pragma unroll
        for (int kk = 0; kk < 2; ++kk)
          acc[ib + i][jb + j] =
              __builtin_amdgcn_mfma_f32_16x16x32_bf16(af[i][kk], bf[j][kk],
                                                      acc[ib + i][jb + j], 0, 0, 0);
    __builtin_amdgcn_s_setprio(0);
  };

  STAGE(0, 0, 0, 0); STAGE(0, 0, 1, 0); STAGE(0, 1, 0, 0); STAGE(0, 1, 1, 0);
  STAGE(1, 0, 0, 1); STAGE(1, 0, 1, 1);
  asm volatile("s_waitcnt vmcnt(4)" ::: "memory");
  BAR();

#pragma unroll
  for (int it = 0; it < 4; ++it) {
    const int s = 2 * it;
    const bool pre = (it < 3);
    // ph1
#pragma unroll
    for (int i = 0; i < 4; ++i) { a0[i][0] = rdA(0, i, 0); a0[i][1] = rdA(0, i, 1); }
#pragma unroll
    for (int j = 0; j < 2; ++j) { bb0[j][0] = rdB(0, j, 0); bb0[j][1] = rdB(0, j, 1); }
    STAGE(1, 1, 0, s + 1);
    BAR(); WAIT_LGKM0();
    MM(a0, bb0, 0, 0);
    BAR();
    // ph2
#pragma unroll
    for (int i = 0; i < 4; ++i) { a1[i][0] = rdA(0, 4 + i, 0); a1[i][1] = rdA(0, 4 + i, 1); }
    STAGE(1, 1, 1, s + 1);
    BAR(); WAIT_LGKM0();
    MM(a1, bb0, 4, 0);
    BAR();
    // ph3
#pragma unroll
    for (int j = 0; j < 2; ++j) { bb1[j][0] = rdB(0, 2 + j, 0); bb1[j][1] = rdB(0, 2 + j, 1); }
    if (pre) STAGE(0, 0, 0, s + 2);
    BAR(); WAIT_LGKM0();
    MM(a0, bb1, 0, 2);
    BAR();
    // ph4
    if (pre) { STAGE(0, 1, 0, s + 2);
               asm volatile("s_waitcnt vmcnt(4)" ::: "memory"); }
    else     { asm volatile("s_waitcnt vmcnt(0)" ::: "memory"); }
    BAR();
    MM(a1, bb1, 4, 2);
    BAR();
    // ph5
#pragma unroll
    for (int i = 0; i < 4; ++i) { a0[i][0] = rdA(1, i, 0); a0[i][1] = rdA(1, i, 1); }
#pragma unroll
    for (int j = 0; j < 2; ++j) { bb0[j][0] = rdB(1, j, 0); bb0[j][1] = rdB(1, j, 1); }
    if (pre) STAGE(0, 0, 1, s + 2);
    BAR(); WAIT_LGKM0();
    MM(a0, bb0, 0, 0);
    BAR();
    // ph6
#pragma unroll
    for (int i = 0; i < 4; ++i) { a1[i][0] = rdA(1, 4 + i, 0); a1[i][1] = rdA(1, 4 + i, 1); }
    if (pre) STAGE(0, 1, 1, s + 2);
    BAR(); WAIT_LGKM0();
    MM(a1, bb0, 4, 0);
    BAR();
    // ph7
#pragma unroll
    for (int j = 0; j < 2; ++j) { bb1[j][0] = rdB(1, 2 + j, 0); bb1[j][1] = rdB(1, 2 + j, 1); }
    if (pre) STAGE(1, 0, 0, s + 3);
    BAR(); WAIT_LGKM0();
    MM(a0, bb1, 0, 2);
    BAR();
    // ph8
    if (pre) { STAGE(1, 0, 1, s + 3);
               asm volatile("s_waitcnt vmcnt(4)" ::: "memory"); }
    BAR();
    MM(a1, bb1, 4, 2);
    BAR();
  }

  // epilogue: row-contiguous cached stores (j innermost)
  const int r0q = (lane >> 4) * 4, cc = lane & 15;
  const int rowbase = (int)a_row0 + wr * 128;
  const int colbase = (int)b_row0 + wc * 64;
  float bia[4]; bool val[4];
#pragma unroll
  for (int j = 0; j < 4; ++j) {
    int n = colbase + j * 16 + cc;
    val[j] = (n < V_);
    bia[j] = val[j] ? bo[n] : 0.f;
  }
#pragma unroll
  for (int i = 0; i < 8; ++i) {
#pragma unroll
    for (int q = 0; q < 4; ++q) {
      size_t rowoff = (size_t)(rowbase + i * 16 + r0q + q) * V_;
#pragma unroll
      for (int j = 0; j < 4; ++j) {
        if (val[j]) Y[rowoff + colbase + j * 16 + cc] = acc[i][j][q] + bia[j];
      }
    }
  }
}

// ---------------------------------------------------------------------------
// fallback path (ws too small): fp32 Wo reg-staged GEMM
// ---------------------------------------------------------------------------
__global__ __launch_bounds__(256) void gemm_out_kernel(
    const bf16* __restrict__ A, const float* __restrict__ Wo,
    const float* __restrict__ bo, float* __restrict__ Y)
{
  __shared__ bf16 As[128 * 64];
  __shared__ bf16 Bs[128 * 64];
  constexpr int K = 512;
  const int tid = threadIdx.x;
  const int wid = tid >> 6, lane = tid & 63;
  const int bm = blockIdx.x, bn = blockIdx.y;
  const int wm = (wid >> 1) * 64, wn = (wid & 1) * 64;
  f32x4 acc[4][4] = {};

  for (int k0 = 0; k0 < K; k0 += 64) {
#pragma unroll
    for (int i = 0; i < 4; ++i) {
      int base = i * 256 + wid * 64;
      int idx = base + lane;
      int row = idx >> 3, col = (idx & 7) << 3;
      gload_lds16(A + ((size_t)bm * 128 + row) * K + (k0 + col), &As[base * 8]);
    }
#pragma unroll
    for (int i = 0; i < 8; ++i) {
      int idx = i * 256 + tid;
      int row = idx >> 4;
      int c4 = (idx & 15) * 4;
      int n = bn * 128 + row;
      int nc = (n < V_) ? n : (V_ - 1);
      f32x4 v = *reinterpret_cast<const f32x4*>(Wo + (size_t)nc * K + k0 + c4);
      bf16x4 t; t[0]=(bf16)v[0]; t[1]=(bf16)v[1]; t[2]=(bf16)v[2]; t[3]=(bf16)v[3];
      *reinterpret_cast<bf16x4*>(&Bs[row * 64 + c4]) = t;
    }
    asm volatile("s_waitcnt vmcnt(0)" ::: "memory");
    __syncthreads();
#pragma unroll
    for (int kk = 0; kk < 2; ++kk) {
      bf16x8 af[4], bb[4];
#pragma unroll
      for (int i = 0; i < 4; ++i)
        af[i] = *reinterpret_cast<const bf16x8*>(
            &As[(wm + i * 16 + (lane & 15)) * 64 + kk * 32 + (lane >> 4) * 8]);
#pragma unroll
      for (int j = 0; j < 4; ++j)
        bb[j] = *reinterpret_cast<const bf16x8*>(
            &Bs[(wn + j * 16 + (lane & 15)) * 64 + kk * 32 + (lane >> 4) * 8]);
#pragma unroll
      for (int i = 0; i < 4; ++i)
#pragma unroll
        for (int j = 0; j < 4; ++j)
          acc[i][j] = __builtin_amdgcn_mfma_f32_16x16x32_bf16(af[i], bb[j], acc[i][j], 0, 0, 0);
    }
    __syncthreads();
  }

  const int r0 = (lane >> 4) * 4, cc = lane & 15;
#pragma unroll
  for (int i = 0; i < 4; ++i)
#pragma unroll
    for (int j = 0; j < 4; ++j) {
      int n = bn * 128 + wn + j * 16 + cc;
      if (n < V_) {
        float bia = bo[n];
#pragma unroll
        for (int q = 0; q < 4; ++q) {
          int mm = bm * 128 + wm + i * 16 + r0 + q;
          Y[(size_t)mm * V_ + n] = acc[i][j][q] + bia;
        }
      }
    }
}

// ---------------------------------------------------------------------------
extern "C" void kernel_launch(void* const* d_in, const int* in_sizes, int n_in,
                              void* d_out, int out_size, void* d_ws, size_t ws_size,
                              hipStream_t stream) {
  const float* x     = (const float*)d_in[0];
  const float* hprev = (const float*)d_in[1];
  const float* Wz    = (const float*)d_in[2];
  const float* bz    = (const float*)d_in[3];
  const float* gz    = (const float*)d_in[4];
  const float* bez   = (const float*)d_in[5];
  const float* Wr    = (const float*)d_in[6];
  const float* br    = (const float*)d_in[7];
  const float* gr    = (const float*)d_in[8];
  const float* ber   = (const float*)d_in[9];
  const float* Wh    = (const float*)d_in[10];
  const float* bh    = (const float*)d_in[11];
  const float* gh    = (const float*)d_in[12];
  const float* beh   = (const float*)d_in[13];
  const float* Wo    = (const float*)d_in[14];
  const float* bo    = (const float*)d_in[15];

  float* out_h = (float*)d_out;
  float* out_y = out_h + (size_t)B_ * H_;

  char* ws = (char*)d_ws;
  bf16*  gin  = (bf16*)(ws);                      // 4 MB   [2048][1024]
  bf16*  wzrh = (bf16*)(ws + ((size_t)4 << 20));  // 3 MB   [1536][1024]
  float* zrp  = (float*)(ws + ((size_t)7 << 20)); // 8 MB   [2048][1024]
  float* zbuf = (float*)(ws + ((size_t)15 << 20));// 4 MB   [2048][512]
  bf16*  cand = (bf16*)(ws + ((size_t)19 << 20)); // 4 MB   [2048][1024]
  float* hpre = (float*)(ws + ((size_t)23 << 20));// 4 MB   [2048][512]
  bf16*  htb  = (bf16*)(ws + ((size_t)27 << 20)); // 2 MB   [2048][512]
  bf16*  wob  = (bf16*)(ws + ((size_t)29 << 20)); // 51.6 MB [VPAD_][512]

  constexpr size_t NEED = ((size_t)29 << 20) + (size_t)VPAD_ * 512 * 2;
  const bool big = (ws_size >= NEED);

  prep_kernel<<<3584, 256, 0, stream>>>(hprev, x, Wz, Wr, Wh, gin, wzrh);

  // zr GEMM (+ first half of Wo conversion hidden in extra blocks)
  gemm64_zr<<<big ? 2304 : 256, 256, 0, stream>>>(gin, wzrh, zrp, Wo, wob);

  // LN z/r (+ second half of Wo conversion + pad)
  ln_zr_kernel<<<big ? 4096 : 2048, 256, 0, stream>>>(
      zrp, bz, br, gz, bez, gr, ber, hprev, x, zbuf, cand, Wo, wob);

  gemm64<<<dim3(32, 4), 256, 0, stream>>>(cand, wzrh + (size_t)1024 * 1024, hpre, B_, 512, K1_);
  ln_h_kernel<<<B_, 256, 0, stream>>>(hpre, bh, gh, beh, zbuf, hprev, out_h, htb);

  if (big) {
    gemm_out256<<<1576, 512, 0, stream>>>(htb, wob, bo, out_y);
  } else {
    gemm_out_kernel<<<dim3(16, 393), 256, 0, stream>>>(htb, Wo, bo, out_y);
  }
}